// Round 1
// baseline (411.033 us; speedup 1.0000x reference)
//
#include <hip/hip_runtime.h>
#include <cstdint>

#define EMBD 1024
#define NH 16
#define DH 64
#define BB 2
#define SS 2048
#define M_TOT (BB*SS)     // 4096
#define N_QKV (3*EMBD)    // 3072

typedef __bf16 bf16_t;
typedef bf16_t bf16x8 __attribute__((ext_vector_type(8)));
typedef float f32x4 __attribute__((ext_vector_type(4)));
typedef unsigned short u16;

static __device__ __forceinline__ u16 f2bf(float f) {
    union { float f; unsigned u; } c; c.f = f;
    unsigned u = c.u;
    unsigned r = (u + 0x7FFFu + ((u >> 16) & 1u)) >> 16;  // RNE
    return (u16)r;
}

// ---------------- cast fp32 -> bf16, 8 elems/thread ----------------
__global__ void cast_f32_bf16(const float* __restrict__ src,
                              u16* __restrict__ dst, int n8) {
    int i = blockIdx.x * blockDim.x + threadIdx.x;
    if (i >= n8) return;
    const float4* s4 = (const float4*)src;
    float4 a = s4[2 * i];
    float4 b = s4[2 * i + 1];
    union { u16 u[8]; uint4 v; } r;
    r.u[0] = f2bf(a.x); r.u[1] = f2bf(a.y); r.u[2] = f2bf(a.z); r.u[3] = f2bf(a.w);
    r.u[4] = f2bf(b.x); r.u[5] = f2bf(b.y); r.u[6] = f2bf(b.z); r.u[7] = f2bf(b.w);
    ((uint4*)dst)[i] = r.v;
}

// ---------------- QKV GEMM: C[i][o] = sum_d x[i][d]*W_in[o][d] + b_in[o] ----
// NT bf16 MFMA GEMM, 128x128 tile, BK=32, 4 waves each 64x64.
// Epilogue scatters into Q [B,H,S,64] (pre-scaled 1/8), K [B,H,S,64], Vt [B,H,64,S].
#define LDS_STRIDE 40   // 32 + 8 pad: 80B rows, 16B aligned, 2-way-free reads
__global__ __launch_bounds__(256) void gemm_qkv(
    const u16* __restrict__ Xb,   // [4096][1024]
    const u16* __restrict__ Wb,   // [3072][1024]
    const float* __restrict__ b_in,
    u16* __restrict__ Q, u16* __restrict__ K, u16* __restrict__ Vt)
{
    __shared__ u16 As[128 * LDS_STRIDE];
    __shared__ u16 Bs[128 * LDS_STRIDE];
    const int t = threadIdx.x;
    const int lane = t & 63, wave = t >> 6;
    const int wm = wave >> 1, wn = wave & 1;
    const int quad = lane >> 4, l16 = lane & 15;
    const int m0 = blockIdx.y * 128, n0 = blockIdx.x * 128;

    f32x4 acc[4][4] = {};

    for (int k0 = 0; k0 < EMBD; k0 += 32) {
#pragma unroll
        for (int i = 0; i < 2; ++i) {
            int idx = i * 256 + t;
            int row = idx >> 2, kc = (idx & 3) * 8;
            uint4 va = *(const uint4*)(Xb + (size_t)(m0 + row) * EMBD + k0 + kc);
            uint4 vb = *(const uint4*)(Wb + (size_t)(n0 + row) * EMBD + k0 + kc);
            *(uint4*)(As + row * LDS_STRIDE + kc) = va;
            *(uint4*)(Bs + row * LDS_STRIDE + kc) = vb;
        }
        __syncthreads();
        bf16x8 af[4], bfr[4];
#pragma unroll
        for (int im = 0; im < 4; ++im)
            af[im] = *(const bf16x8*)(As + (wm * 64 + im * 16 + l16) * LDS_STRIDE + quad * 8);
#pragma unroll
        for (int in = 0; in < 4; ++in)
            bfr[in] = *(const bf16x8*)(Bs + (wn * 64 + in * 16 + l16) * LDS_STRIDE + quad * 8);
#pragma unroll
        for (int im = 0; im < 4; ++im)
#pragma unroll
            for (int in = 0; in < 4; ++in)
                acc[im][in] = __builtin_amdgcn_mfma_f32_16x16x32_bf16(
                    af[im], bfr[in], acc[im][in], 0, 0, 0);
        __syncthreads();
    }

    // epilogue: C/D layout col=lane&15, row=quad*4+reg
#pragma unroll
    for (int im = 0; im < 4; ++im) {
        int rbase = m0 + wm * 64 + im * 16 + quad * 4;
#pragma unroll
        for (int in = 0; in < 4; ++in) {
            int col = n0 + wn * 64 + in * 16 + l16;
            float bias = b_in[col];
#pragma unroll
            for (int j = 0; j < 4; ++j) {
                float v = acc[im][in][j] + bias;
                int r = rbase + j;
                int b = r >> 11, s = r & (SS - 1);
                if (col < EMBD) {
                    int h = col >> 6, d = col & 63;
                    Q[(((size_t)(b * NH + h) * SS) + s) * DH + d] = f2bf(v * 0.125f);
                } else if (col < 2 * EMBD) {
                    int c = col - EMBD; int h = c >> 6, d = c & 63;
                    K[(((size_t)(b * NH + h) * SS) + s) * DH + d] = f2bf(v);
                } else {
                    int c = col - 2 * EMBD; int h = c >> 6, d = c & 63;
                    Vt[((size_t)(b * NH + h) * DH + d) * SS + s] = f2bf(v);
                }
            }
        }
    }
}

// ---------------- flash attention: 1 wave = 16 queries, 32 keys/iter --------
__global__ __launch_bounds__(256) void attn(
    const u16* __restrict__ Q, const u16* __restrict__ K,
    const u16* __restrict__ Vt, u16* __restrict__ AO)
{
    __shared__ u16 P[4][16 * LDS_STRIDE];
    const int t = threadIdx.x;
    const int lane = t & 63, w = t >> 6;
    const int quad = lane >> 4, l16 = lane & 15;
    const int bh = blockIdx.x >> 5;       // 0..31 (b*16+h)
    const int qt = blockIdx.x & 31;
    const int q0 = qt * 64 + w * 16;

    const u16* Qh = Q + ((size_t)bh * SS + q0) * DH;
    const u16* Kh = K + (size_t)bh * SS * DH;
    const u16* Vh = Vt + (size_t)bh * DH * SS;

    // Q fragments (A-layout: m=lane&15, k=quad*8+j), K-dim 64 -> two frags
    bf16x8 qa0 = *(const bf16x8*)(Qh + l16 * DH + quad * 8);
    bf16x8 qa1 = *(const bf16x8*)(Qh + l16 * DH + 32 + quad * 8);

    f32x4 o[4] = {};
    float mrow[4] = {-1e30f, -1e30f, -1e30f, -1e30f};
    float lrow[4] = {0.f, 0.f, 0.f, 0.f};

    for (int j0 = 0; j0 < SS; j0 += 32) {
        // B-frags for keys (n=lane&15 -> key, k=quad*8+j -> d)
        bf16x8 b0lo = *(const bf16x8*)(Kh + (size_t)(j0 + l16) * DH + quad * 8);
        bf16x8 b0hi = *(const bf16x8*)(Kh + (size_t)(j0 + l16) * DH + 32 + quad * 8);
        bf16x8 b1lo = *(const bf16x8*)(Kh + (size_t)(j0 + 16 + l16) * DH + quad * 8);
        bf16x8 b1hi = *(const bf16x8*)(Kh + (size_t)(j0 + 16 + l16) * DH + 32 + quad * 8);
        f32x4 s0 = {0.f, 0.f, 0.f, 0.f};
        f32x4 s1 = {0.f, 0.f, 0.f, 0.f};
        s0 = __builtin_amdgcn_mfma_f32_16x16x32_bf16(qa0, b0lo, s0, 0, 0, 0);
        s0 = __builtin_amdgcn_mfma_f32_16x16x32_bf16(qa1, b0hi, s0, 0, 0, 0);
        s1 = __builtin_amdgcn_mfma_f32_16x16x32_bf16(qa0, b1lo, s1, 0, 0, 0);
        s1 = __builtin_amdgcn_mfma_f32_16x16x32_bf16(qa1, b1hi, s1, 0, 0, 0);

        // online softmax per row (row = quad*4 + j, cols across 16 lanes)
        float pr0[4], pr1[4], alpha[4];
#pragma unroll
        for (int j = 0; j < 4; ++j) {
            float a = s0[j], b = s1[j];
            float mx = fmaxf(a, b);
#pragma unroll
            for (int off = 1; off < 16; off <<= 1)
                mx = fmaxf(mx, __shfl_xor(mx, off, 64));
            float mn = fmaxf(mrow[j], mx);
            float al = __expf(mrow[j] - mn);
            float p0 = __expf(a - mn);
            float p1 = __expf(b - mn);
            float rs = p0 + p1;
#pragma unroll
            for (int off = 1; off < 16; off <<= 1)
                rs += __shfl_xor(rs, off, 64);
            lrow[j] = lrow[j] * al + rs;
            mrow[j] = mn;
            alpha[j] = al;
            pr0[j] = p0; pr1[j] = p1;
        }
#pragma unroll
        for (int dt = 0; dt < 4; ++dt)
#pragma unroll
            for (int j = 0; j < 4; ++j)
                o[dt][j] *= alpha[j];

        // P (C-layout) -> LDS -> A-layout
        u16* Pw = &P[w][0];
#pragma unroll
        for (int j = 0; j < 4; ++j) {
            Pw[(quad * 4 + j) * LDS_STRIDE + l16] = f2bf(pr0[j]);
            Pw[(quad * 4 + j) * LDS_STRIDE + 16 + l16] = f2bf(pr1[j]);
        }
        __syncthreads();
        bf16x8 pa = *(const bf16x8*)(Pw + l16 * LDS_STRIDE + quad * 8);
        // PV: B-frag from Vt (n=lane&15 -> d, k=quad*8+j -> key)
#pragma unroll
        for (int dt = 0; dt < 4; ++dt) {
            bf16x8 bv = *(const bf16x8*)(Vh + (size_t)(dt * 16 + l16) * SS + j0 + quad * 8);
            o[dt] = __builtin_amdgcn_mfma_f32_16x16x32_bf16(pa, bv, o[dt], 0, 0, 0);
        }
        __syncthreads();
    }

    // normalize and write attn-out bf16 [4096][1024]
    const int b = bh >> 4, h = bh & 15;
    float rl[4];
#pragma unroll
    for (int j = 0; j < 4; ++j) rl[j] = 1.0f / lrow[j];
#pragma unroll
    for (int dt = 0; dt < 4; ++dt)
#pragma unroll
        for (int j = 0; j < 4; ++j) {
            int q = q0 + quad * 4 + j;
            AO[((size_t)(b * SS + q)) * EMBD + h * DH + dt * 16 + l16] =
                f2bf(o[dt][j] * rl[j]);
        }
}

// ---------------- out projection GEMM: out = AO @ W_out^T + b_out (fp32 out)
__global__ __launch_bounds__(256) void gemm_out(
    const u16* __restrict__ Ab,   // [4096][1024]
    const u16* __restrict__ Wb,   // [1024][1024]
    const float* __restrict__ b_out,
    float* __restrict__ Out)
{
    __shared__ u16 As[128 * LDS_STRIDE];
    __shared__ u16 Bs[128 * LDS_STRIDE];
    const int t = threadIdx.x;
    const int lane = t & 63, wave = t >> 6;
    const int wm = wave >> 1, wn = wave & 1;
    const int quad = lane >> 4, l16 = lane & 15;
    const int m0 = blockIdx.y * 128, n0 = blockIdx.x * 128;

    f32x4 acc[4][4] = {};

    for (int k0 = 0; k0 < EMBD; k0 += 32) {
#pragma unroll
        for (int i = 0; i < 2; ++i) {
            int idx = i * 256 + t;
            int row = idx >> 2, kc = (idx & 3) * 8;
            uint4 va = *(const uint4*)(Ab + (size_t)(m0 + row) * EMBD + k0 + kc);
            uint4 vb = *(const uint4*)(Wb + (size_t)(n0 + row) * EMBD + k0 + kc);
            *(uint4*)(As + row * LDS_STRIDE + kc) = va;
            *(uint4*)(Bs + row * LDS_STRIDE + kc) = vb;
        }
        __syncthreads();
        bf16x8 af[4], bfr[4];
#pragma unroll
        for (int im = 0; im < 4; ++im)
            af[im] = *(const bf16x8*)(As + (wm * 64 + im * 16 + l16) * LDS_STRIDE + quad * 8);
#pragma unroll
        for (int in = 0; in < 4; ++in)
            bfr[in] = *(const bf16x8*)(Bs + (wn * 64 + in * 16 + l16) * LDS_STRIDE + quad * 8);
#pragma unroll
        for (int im = 0; im < 4; ++im)
#pragma unroll
            for (int in = 0; in < 4; ++in)
                acc[im][in] = __builtin_amdgcn_mfma_f32_16x16x32_bf16(
                    af[im], bfr[in], acc[im][in], 0, 0, 0);
        __syncthreads();
    }

#pragma unroll
    for (int im = 0; im < 4; ++im) {
        int rbase = m0 + wm * 64 + im * 16 + quad * 4;
#pragma unroll
        for (int in = 0; in < 4; ++in) {
            int col = n0 + wn * 64 + in * 16 + l16;
            float bias = b_out[col];
#pragma unroll
            for (int j = 0; j < 4; ++j)
                Out[(size_t)(rbase + j) * EMBD + col] = acc[im][in][j] + bias;
        }
    }
}

extern "C" void kernel_launch(void* const* d_in, const int* in_sizes, int n_in,
                              void* d_out, int out_size, void* d_ws, size_t ws_size,
                              hipStream_t stream)
{
    (void)in_sizes; (void)n_in; (void)out_size; (void)ws_size;
    const float* x     = (const float*)d_in[0];
    const float* W_in  = (const float*)d_in[1];
    const float* b_in  = (const float*)d_in[2];
    const float* W_out = (const float*)d_in[3];
    const float* b_out = (const float*)d_in[4];
    float* out = (float*)d_out;

    char* ws = (char*)d_ws;
    u16* xb  = (u16*)(ws);                          //  8 MB: x bf16 [4096][1024]
    u16* wib = (u16*)(ws + 8u  * 1024 * 1024);      //  6 MB: W_in bf16
    u16* wob = (u16*)(ws + 14u * 1024 * 1024);      //  2 MB: W_out bf16
    u16* Qw  = (u16*)(ws + 16u * 1024 * 1024);      //  8 MB: Q [B,H,S,64] (x1/8)
    u16* Kw  = (u16*)(ws + 24u * 1024 * 1024);      //  8 MB: K [B,H,S,64]
    u16* Vtw = (u16*)(ws + 32u * 1024 * 1024);      //  8 MB: Vt [B,H,64,S]
    u16* AO  = (u16*)(ws + 40u * 1024 * 1024);      //  8 MB: attn out bf16

    cast_f32_bf16<<<(M_TOT * EMBD / 8 + 255) / 256, 256, 0, stream>>>(x, xb, M_TOT * EMBD / 8);
    cast_f32_bf16<<<(N_QKV * EMBD / 8 + 255) / 256, 256, 0, stream>>>(W_in, wib, N_QKV * EMBD / 8);
    cast_f32_bf16<<<(EMBD * EMBD / 8 + 255) / 256, 256, 0, stream>>>(W_out, wob, EMBD * EMBD / 8);

    gemm_qkv<<<dim3(N_QKV / 128, M_TOT / 128), 256, 0, stream>>>(xb, wib, b_in, Qw, Kw, Vtw);
    attn<<<32 * (SS / 64), 256, 0, stream>>>(Qw, Kw, Vtw, AO);
    gemm_out<<<dim3(EMBD / 128, M_TOT / 128), 256, 0, stream>>>(AO, wob, b_out, out);
}